// Round 9
// baseline (110.114 us; speedup 1.0000x reference)
//
#include <hip/hip_runtime.h>
#include <hip/hip_bf16.h>
#include <hip/hip_fp16.h>
#include <math.h>

#define DIM   256
#define NHEAD 8
#define HD    32
#define NTOK  4096
#define GRD   64
#define BATCH 2
#define MTOT  (BATCH * NTOK)   // 8192

typedef __attribute__((ext_vector_type(8))) short bf16x8;
typedef __attribute__((ext_vector_type(4))) float f32x4;
typedef _Float16 h8 __attribute__((ext_vector_type(8)));
typedef _Float16 h2v __attribute__((ext_vector_type(2)));
typedef __fp16 fp16x2 __attribute__((ext_vector_type(2)));

#if defined(__has_builtin)
#if __has_builtin(__builtin_amdgcn_fdot2)
#define HAVE_DOT2 1
#endif
#endif
#ifndef HAVE_DOT2
#define HAVE_DOT2 0
#endif

static __device__ __forceinline__ unsigned short f2b(float f) {
  __hip_bfloat16 h = __float2bfloat16(f);
  union { __hip_bfloat16 h; unsigned short u; } cv;
  cv.h = h;
  return cv.u;
}

static __device__ __forceinline__ bf16x8 pack8(float4 a0, float4 a1) {
  union { bf16x8 v; unsigned short u[8]; } o;
  o.u[0] = f2b(a0.x); o.u[1] = f2b(a0.y); o.u[2] = f2b(a0.z); o.u[3] = f2b(a0.w);
  o.u[4] = f2b(a1.x); o.u[5] = f2b(a1.y); o.u[6] = f2b(a1.z); o.u[7] = f2b(a1.w);
  return o.v;
}

// ---------------- GEMM1: qkv = x(fp32) @ Wqkv(fp32)^T -> planar fp16 --------
// 64x128 tile (full-GPU grid: 6 x 128 = 768 blocks), BK=32, 4 waves (2x2 of
// 32x64). Both operands cast fp32->bf16 during reg-staging (pitch 40 halfs).
__global__ __launch_bounds__(256) void gemm_qkv(const float* __restrict__ A,
                                                const float* __restrict__ Bw,
                                                _Float16* __restrict__ Cout) {
  const int K = 256;
  __shared__ __hip_bfloat16 As[64 * 40];
  __shared__ __hip_bfloat16 Bs[128 * 40];
  const int tid = threadIdx.x;
  const int l = tid & 63, w = tid >> 6;
  const int bm = blockIdx.y * 64, bn = blockIdx.x * 128;
  const int wr = w >> 1, wc = w & 1;
  const int lr = l & 15, kh = l >> 4;
  const int lrow = tid >> 2, lcol = (tid & 3) * 8;   // staging coords

  f32x4 acc[2][4];
  #pragma unroll
  for (int i = 0; i < 2; ++i)
    #pragma unroll
    for (int j = 0; j < 4; ++j)
      acc[i][j] = (f32x4){0.f, 0.f, 0.f, 0.f};

  for (int k0 = 0; k0 < K; k0 += 32) {
    // A: 64 rows, 1 chunk/thread
    {
      const float* ga = A + (size_t)(bm + lrow) * K + k0 + lcol;
      float4 a0 = *(const float4*)ga, a1 = *(const float4*)(ga + 4);
      *(bf16x8*)&As[lrow * 40 + lcol] = pack8(a0, a1);
    }
    // B: 128 rows, 2 chunks/thread
    #pragma unroll
    for (int i = 0; i < 2; ++i) {
      const int row = i * 64 + lrow;
      const float* gb = Bw + (size_t)(bn + row) * K + k0 + lcol;
      float4 b0 = *(const float4*)gb, b1 = *(const float4*)(gb + 4);
      *(bf16x8*)&Bs[row * 40 + lcol] = pack8(b0, b1);
    }
    __syncthreads();

    bf16x8 af[2], bfr[4];
    #pragma unroll
    for (int f = 0; f < 2; ++f)
      af[f] = *(const bf16x8*)&As[(wr * 32 + f * 16 + lr) * 40 + kh * 8];
    #pragma unroll
    for (int f = 0; f < 4; ++f)
      bfr[f] = *(const bf16x8*)&Bs[(wc * 64 + f * 16 + lr) * 40 + kh * 8];
    #pragma unroll
    for (int fi = 0; fi < 2; ++fi)
      #pragma unroll
      for (int fj = 0; fj < 4; ++fj)
        acc[fi][fj] = __builtin_amdgcn_mfma_f32_16x16x32_bf16(af[fi], bfr[fj], acc[fi][fj], 0, 0, 0);
    __syncthreads();
  }

  #pragma unroll
  for (int fi = 0; fi < 2; ++fi)
    #pragma unroll
    for (int fj = 0; fj < 4; ++fj)
      #pragma unroll
      for (int rr = 0; rr < 4; ++rr) {
        const int m = bm + wr * 32 + fi * 16 + kh * 4 + rr;
        const int n = bn + wc * 64 + fj * 16 + lr;
        const int sel = n >> 8, rem = n & 255;
        const int hh = rem >> 5, d = rem & 31;
        const int bb = m >> 12, tok = m & 4095;
        Cout[((size_t)(sel * 16 + bb * 8 + hh) * NTOK + tok) * HD + d] =
            (_Float16)acc[fi][fj][rr];
      }
}

// ---------------- GEMM2: out = attn(bf16) @ Wproj(fp32)^T + bias (fp32) -----
// 64x128 tile -> grid (2, 128) = 256 blocks (was 128: half the GPU idle).
__global__ __launch_bounds__(256) void gemm_proj(const __hip_bfloat16* __restrict__ A,
                                                 const float* __restrict__ Bw,
                                                 const float* __restrict__ bias,
                                                 float* __restrict__ Cout) {
  const int K = 256, N = 256;
  __shared__ __hip_bfloat16 As[64 * 32];    // linear: global_load_lds dest
  __shared__ __hip_bfloat16 Bs[128 * 40];   // padded: reg-staged
  const int tid = threadIdx.x;
  const int l = tid & 63, w = tid >> 6;
  const int bm = blockIdx.y * 64, bn = blockIdx.x * 128;
  const int wr = w >> 1, wc = w & 1;
  const int lr = l & 15, kh = l >> 4;
  const int lrow = tid >> 2, lcol = (tid & 3) * 8;

  f32x4 acc[2][4];
  #pragma unroll
  for (int i = 0; i < 2; ++i)
    #pragma unroll
    for (int j = 0; j < 4; ++j)
      acc[i][j] = (f32x4){0.f, 0.f, 0.f, 0.f};

  for (int k0 = 0; k0 < K; k0 += 32) {
    // A: 64x32 bf16 = 1 glds chunk/thread (dest linear: elem off = tid*8)
    {
      const __hip_bfloat16* ga = A + (size_t)(bm + lrow) * K + k0 + lcol;
      __builtin_amdgcn_global_load_lds(
          (const __attribute__((address_space(1))) void*)ga,
          (__attribute__((address_space(3))) void*)&As[w * 512], 16, 0, 0);
    }
    // B: 128 rows fp32 -> bf16, 2 chunks/thread
    #pragma unroll
    for (int i = 0; i < 2; ++i) {
      const int row = i * 64 + lrow;
      const float* gb = Bw + (size_t)(bn + row) * K + k0 + lcol;
      float4 b0 = *(const float4*)gb, b1 = *(const float4*)(gb + 4);
      *(bf16x8*)&Bs[row * 40 + lcol] = pack8(b0, b1);
    }
    __syncthreads();

    bf16x8 af[2], bfr[4];
    #pragma unroll
    for (int f = 0; f < 2; ++f)
      af[f] = *(const bf16x8*)&As[(wr * 32 + f * 16 + lr) * 32 + kh * 8];
    #pragma unroll
    for (int f = 0; f < 4; ++f)
      bfr[f] = *(const bf16x8*)&Bs[(wc * 64 + f * 16 + lr) * 40 + kh * 8];
    #pragma unroll
    for (int fi = 0; fi < 2; ++fi)
      #pragma unroll
      for (int fj = 0; fj < 4; ++fj)
        acc[fi][fj] = __builtin_amdgcn_mfma_f32_16x16x32_bf16(af[fi], bfr[fj], acc[fi][fj], 0, 0, 0);
    __syncthreads();
  }

  #pragma unroll
  for (int fi = 0; fi < 2; ++fi)
    #pragma unroll
    for (int fj = 0; fj < 4; ++fj)
      #pragma unroll
      for (int rr = 0; rr < 4; ++rr) {
        const int m = bm + wr * 32 + fi * 16 + kh * 4 + rr;
        const int n = bn + wc * 64 + fj * 16 + lr;
        Cout[(size_t)m * N + n] = acc[fi][fj][rr] + bias[n];
      }
}

// ---------------- Local attention: 2 query-rows per block -------------------
// Block = 512 threads = one (b,h,row-pair rp). K/V rows 2rp-3..2rp+4 staged
// via global_load_lds with XOR swizzle x = ((tk>>1)^(tk>>6))&3 (both sides).
// QK: thread (qr, c, s) computes slices dr {s-3, s+1} (14 keys, 4 reads each).
// PV restructured (DS-pipe relief): p's normalized, packed fp16, exchanged
// across the 4 s-lanes with 21 shuffles; each lane then accumulates ONLY its
// 8 dims (s*8..s*8+8) over all 56 slots with 1 ds_read_b128 per key.
__global__ __launch_bounds__(512) void local_attn(const _Float16* __restrict__ qkv,
                                                  const float* __restrict__ temp,
                                                  __hip_bfloat16* __restrict__ attn_out) {
  __shared__ _Float16 Ks[512 * 32];
  __shared__ _Float16 Vs[512 * 32];

  const int P = blockIdx.x;
  const int L = (P & 7) * 64 + (P >> 3);    // XCD-chunked remap (512 = 8*64)
  const int plane = L >> 5, rp = L & 31;
  const int b = plane >> 3, h = plane & 7;
  const int t = threadIdx.x;
  const int qr = t >> 8, c = (t >> 2) & 63, s = t & 3;
  const int r = rp * 2 + qr;

  const float scale = 0.17677669529663687f * temp[0];

  const _Float16* qplane = qkv + (size_t)(b * 8 + h) * (NTOK * HD);
  const _Float16* kplane = qkv + (size_t)(16 + b * 8 + h) * (NTOK * HD);
  const _Float16* vplane = qkv + (size_t)(32 + b * 8 + h) * (NTOK * HD);

  // ---- stage 8 grid rows of K/V (clamped), source pre-swizzled -------------
  {
    const int rbase = rp * 2 - 3;
    const int wbase = t & ~63;              // wave-uniform
    #pragma unroll
    for (int i = 0; i < 4; ++i) {
      const int id = i * 512 + t;
      const int drp = id >> 8;              // 0..7 (wave-uniform)
      const int tokloc = (id >> 2) & 63;
      const int jjp = id & 3;
      const int x = ((tokloc >> 1) ^ drp) & 3;
      const int jj = jjp ^ x;
      int row = rbase + drp;
      row = row < 0 ? 0 : (row > 63 ? 63 : row);
      const _Float16* src = kplane + (size_t)row * 2048 + tokloc * 32 + jj * 8;
      const _Float16* srv = vplane + (size_t)row * 2048 + tokloc * 32 + jj * 8;
      const int dbase = (i * 512 + wbase) * 8;
      __builtin_amdgcn_global_load_lds(
          (const __attribute__((address_space(1))) void*)src,
          (__attribute__((address_space(3))) void*)&Ks[dbase], 16, 0, 0);
      __builtin_amdgcn_global_load_lds(
          (const __attribute__((address_space(1))) void*)srv,
          (__attribute__((address_space(3))) void*)&Vs[dbase], 16, 0, 0);
    }
  }

  // ---- Q (own query) as fp16 pairs ----------------------------------------
  union { h8 v; h2v p[4]; } qu[4];
  {
    const _Float16* qrp_ = qplane + (size_t)(r * GRD + c) * HD;
    #pragma unroll
    for (int jj = 0; jj < 4; ++jj) qu[jj].v = *(const h8*)&qrp_[jj * 8];
  }
  __syncthreads();

  // ---- QK scores (slice s: dr = s-3 (i=0), s+1 (i=1, s<3 only)) -----------
  const char* KB = (const char*)Ks;
  const char* VB = (const char*)Vs;
  float sc[14];
  float mx = -INFINITY;
  const int ndr = (s < 3) ? 2 : 1;
  #pragma unroll
  for (int i = 0; i < 2; ++i) {
    const int dr = s - 3 + 4 * i;
    const int drp = dr + 3 + qr;            // staged row index 0..7
    const int rr = r + dr;
    const bool rowok = (i < ndr) && (rr >= 0) && (rr < GRD);
    #pragma unroll
    for (int dc = -3; dc <= 3; ++dc) {
      const int cc = c + dc;
      const bool ok = rowok && (cc >= 0) && (cc < GRD);
      int tk = drp * 64 + cc;
      tk = tk < 0 ? 0 : (tk > 511 ? 511 : tk);
      const int x = ((tk >> 1) ^ (tk >> 6)) & 3;
      const int sb = (tk << 6) ^ (x << 4);  // byte base, bits 4-5 swizzled
      float dot = 0.f;
      #pragma unroll
      for (int jj = 0; jj < 4; ++jj) {
        union { h8 v; h2v p[4]; } kk;
        kk.v = *(const h8*)(KB + (sb ^ (jj << 4)));
        #pragma unroll
        for (int kx = 0; kx < 4; ++kx) {
#if HAVE_DOT2
          dot = __builtin_amdgcn_fdot2(kk.p[kx], qu[jj].p[kx], dot, false);
#else
          dot = fmaf((float)kk.p[kx][0], (float)qu[jj].p[kx][0], dot);
          dot = fmaf((float)kk.p[kx][1], (float)qu[jj].p[kx][1], dot);
#endif
        }
      }
      const float v = ok ? dot * scale : -INFINITY;
      sc[i * 7 + dc + 3] = v;
      mx = fmaxf(mx, v);
    }
  }

  // group max over the 4 slice-lanes (slice 3 i=0 is dr=0: always valid)
  mx = fmaxf(mx, __shfl_xor(mx, 1));
  mx = fmaxf(mx, __shfl_xor(mx, 2));

  float psum = 0.f;
  #pragma unroll
  for (int i = 0; i < 14; ++i) {
    float e = __expf(sc[i] - mx);   // exp(-inf - finite) = 0 for masked
    sc[i] = e;
    psum += e;
  }
  psum += __shfl_xor(psum, 1);
  psum += __shfl_xor(psum, 2);
  const float inv = 1.0f / psum;

  // ---- exchange normalized p's (fp16-packed) across the 4 s-lanes ----------
  unsigned int mine[7], r1v[7], r2a[7], r2b[7];
  #pragma unroll
  for (int j = 0; j < 7; ++j) {
    fp16x2 hp = __builtin_amdgcn_cvt_pkrtz(sc[2 * j] * inv, sc[2 * j + 1] * inv);
    union { fp16x2 h; unsigned int u; } cv; cv.h = hp;
    mine[j] = cv.u;
  }
  #pragma unroll
  for (int j = 0; j < 7; ++j) r1v[j] = (unsigned)__shfl_xor((int)mine[j], 1);
  #pragma unroll
  for (int j = 0; j < 7; ++j) r2a[j] = (unsigned)__shfl_xor((int)mine[j], 2);
  #pragma unroll
  for (int j = 0; j < 7; ++j) r2b[j] = (unsigned)__shfl_xor((int)r1v[j], 2);

  // ---- PV: this lane's 8 dims (s*8..s*8+8) over all 4 origin slices --------
  float o[8];
  #pragma unroll
  for (int i = 0; i < 8; ++i) o[i] = 0.f;

  #pragma unroll
  for (int ss = 0; ss < 4; ++ss) {
    const unsigned int* set = (ss == 0) ? mine : (ss == 1) ? r1v
                             : (ss == 2) ? r2a : r2b;   // static after unroll
    const int sp = s ^ ss;                  // origin slice (runtime, addr only)
    #pragma unroll
    for (int j = 0; j < 7; ++j) {
      union { unsigned int u; h2v h; } pp; pp.u = set[j];
      #pragma unroll
      for (int half = 0; half < 2; ++half) {
        const int slot = 2 * j + half;      // compile-time
        const int ii = slot / 7;
        const int dc = (slot % 7) - 3;
        const float p = (float)pp.h[half];  // masked/out-of-slice slots are 0
        int tk = (sp + 4 * ii + qr) * 64 + c + dc;
        tk = tk < 0 ? 0 : (tk > 511 ? 511 : tk);
        const int x = ((tk >> 1) ^ (tk >> 6)) & 3;
        union { h8 v; h2v p2[4]; } vv;
        vv.v = *(const h8*)(VB + (tk << 6) + (((s ^ x) & 3) << 4));
        #pragma unroll
        for (int kx = 0; kx < 4; ++kx) {
          o[kx * 2 + 0] = fmaf(p, (float)vv.p2[kx][0], o[kx * 2 + 0]);
          o[kx * 2 + 1] = fmaf(p, (float)vv.p2[kx][1], o[kx * 2 + 1]);
        }
      }
    }
  }

  // lane s writes dims [s*8, s*8+8) as bf16 (one 16 B store) — no butterfly
  union { uint4 u; unsigned short sh[8]; } pk;
  #pragma unroll
  for (int j = 0; j < 8; ++j) pk.sh[j] = f2b(o[j]);
  __hip_bfloat16* dst = attn_out + ((size_t)(b * NTOK + r * GRD + c)) * DIM + h * HD + s * 8;
  *(uint4*)dst = pk.u;
}

extern "C" void kernel_launch(void* const* d_in, const int* in_sizes, int n_in,
                              void* d_out, int out_size, void* d_ws, size_t ws_size,
                              hipStream_t stream) {
  const float* x     = (const float*)d_in[0];
  const float* Wqkv  = (const float*)d_in[1];
  const float* Wproj = (const float*)d_in[2];
  const float* bproj = (const float*)d_in[3];
  const float* temp  = (const float*)d_in[4];
  float* out = (float*)d_out;

  // workspace layout (bytes):
  //   [0, 12582912)            qkv planar fp16: 48 planes of [4096][32]
  //   [25165824, 29360128)     attn_bf16 [8192][256]
  char* ws = (char*)d_ws;
  _Float16* qkv_f16       = (_Float16*)ws;
  __hip_bfloat16* attn_bf = (__hip_bfloat16*)(ws + 25165824);

  // 1) qkv = x @ Wqkv^T (fused fp32->bf16 cast) -> planar fp16
  {
    dim3 grid(3 * DIM / 128, MTOT / 64);    // (6, 128) = 768 blocks
    gemm_qkv<<<grid, 256, 0, stream>>>(x, Wqkv, qkv_f16);
  }
  // 2) local attention -> attn_bf [8192][256] bf16
  local_attn<<<BATCH * NHEAD * (GRD / 2), 512, 0, stream>>>(qkv_f16, temp, attn_bf);

  // 3) out = attn @ Wproj^T + bias (fused Wproj cast, fp32 out)
  {
    dim3 grid(DIM / 128, MTOT / 64);        // (2, 128) = 256 blocks
    gemm_proj<<<grid, 256, 0, stream>>>(attn_bf, Wproj, bproj, out);
  }
}

// Round 10
// 51.849 us; speedup vs baseline: 2.1237x; 2.1237x over previous
//
#include <hip/hip_runtime.h>
#include <hip/hip_bf16.h>
#include <hip/hip_fp16.h>
#include <math.h>

#define DIM   256
#define NHEAD 8
#define HD    32
#define NTOK  4096
#define GRD   64
#define BATCH 2
#define MTOT  (BATCH * NTOK)   // 8192

typedef __attribute__((ext_vector_type(8))) short bf16x8;
typedef __attribute__((ext_vector_type(4))) float f32x4;
typedef _Float16 h8 __attribute__((ext_vector_type(8)));
typedef _Float16 h2v __attribute__((ext_vector_type(2)));

#if defined(__has_builtin)
#if __has_builtin(__builtin_amdgcn_fdot2)
#define HAVE_DOT2 1
#endif
#endif
#ifndef HAVE_DOT2
#define HAVE_DOT2 0
#endif

static __device__ __forceinline__ unsigned short f2b(float f) {
  __hip_bfloat16 h = __float2bfloat16(f);
  union { __hip_bfloat16 h; unsigned short u; } cv;
  cv.h = h;
  return cv.u;
}

static __device__ __forceinline__ bf16x8 pack8(float4 a0, float4 a1) {
  union { bf16x8 v; unsigned short u[8]; } o;
  o.u[0] = f2b(a0.x); o.u[1] = f2b(a0.y); o.u[2] = f2b(a0.z); o.u[3] = f2b(a0.w);
  o.u[4] = f2b(a1.x); o.u[5] = f2b(a1.y); o.u[6] = f2b(a1.z); o.u[7] = f2b(a1.w);
  return o.v;
}

// ---------------- GEMM1: qkv = x(fp32) @ Wqkv(fp32)^T -> planar fp16 --------
// 64x128 tile (full-GPU grid: 6 x 128 = 768 blocks), BK=32, 4 waves (2x2 of
// 32x64). Both operands cast fp32->bf16 during reg-staging (pitch 40 halfs).
__global__ __launch_bounds__(256) void gemm_qkv(const float* __restrict__ A,
                                                const float* __restrict__ Bw,
                                                _Float16* __restrict__ Cout) {
  const int K = 256;
  __shared__ __hip_bfloat16 As[64 * 40];
  __shared__ __hip_bfloat16 Bs[128 * 40];
  const int tid = threadIdx.x;
  const int l = tid & 63, w = tid >> 6;
  const int bm = blockIdx.y * 64, bn = blockIdx.x * 128;
  const int wr = w >> 1, wc = w & 1;
  const int lr = l & 15, kh = l >> 4;
  const int lrow = tid >> 2, lcol = (tid & 3) * 8;   // staging coords

  f32x4 acc[2][4];
  #pragma unroll
  for (int i = 0; i < 2; ++i)
    #pragma unroll
    for (int j = 0; j < 4; ++j)
      acc[i][j] = (f32x4){0.f, 0.f, 0.f, 0.f};

  for (int k0 = 0; k0 < K; k0 += 32) {
    // A: 64 rows, 1 chunk/thread
    {
      const float* ga = A + (size_t)(bm + lrow) * K + k0 + lcol;
      float4 a0 = *(const float4*)ga, a1 = *(const float4*)(ga + 4);
      *(bf16x8*)&As[lrow * 40 + lcol] = pack8(a0, a1);
    }
    // B: 128 rows, 2 chunks/thread
    #pragma unroll
    for (int i = 0; i < 2; ++i) {
      const int row = i * 64 + lrow;
      const float* gb = Bw + (size_t)(bn + row) * K + k0 + lcol;
      float4 b0 = *(const float4*)gb, b1 = *(const float4*)(gb + 4);
      *(bf16x8*)&Bs[row * 40 + lcol] = pack8(b0, b1);
    }
    __syncthreads();

    bf16x8 af[2], bfr[4];
    #pragma unroll
    for (int f = 0; f < 2; ++f)
      af[f] = *(const bf16x8*)&As[(wr * 32 + f * 16 + lr) * 40 + kh * 8];
    #pragma unroll
    for (int f = 0; f < 4; ++f)
      bfr[f] = *(const bf16x8*)&Bs[(wc * 64 + f * 16 + lr) * 40 + kh * 8];
    #pragma unroll
    for (int fi = 0; fi < 2; ++fi)
      #pragma unroll
      for (int fj = 0; fj < 4; ++fj)
        acc[fi][fj] = __builtin_amdgcn_mfma_f32_16x16x32_bf16(af[fi], bfr[fj], acc[fi][fj], 0, 0, 0);
    __syncthreads();
  }

  #pragma unroll
  for (int fi = 0; fi < 2; ++fi)
    #pragma unroll
    for (int fj = 0; fj < 4; ++fj)
      #pragma unroll
      for (int rr = 0; rr < 4; ++rr) {
        const int m = bm + wr * 32 + fi * 16 + kh * 4 + rr;
        const int n = bn + wc * 64 + fj * 16 + lr;
        const int sel = n >> 8, rem = n & 255;
        const int hh = rem >> 5, d = rem & 31;
        const int bb = m >> 12, tok = m & 4095;
        Cout[((size_t)(sel * 16 + bb * 8 + hh) * NTOK + tok) * HD + d] =
            (_Float16)acc[fi][fj][rr];
      }
}

// ---------------- GEMM2: out = attn(bf16) @ Wproj(fp32)^T + bias (fp32) -----
// 64x128 tile -> grid (2, 128) = 256 blocks (full GPU).
__global__ __launch_bounds__(256) void gemm_proj(const __hip_bfloat16* __restrict__ A,
                                                 const float* __restrict__ Bw,
                                                 const float* __restrict__ bias,
                                                 float* __restrict__ Cout) {
  const int K = 256, N = 256;
  __shared__ __hip_bfloat16 As[64 * 32];    // linear: global_load_lds dest
  __shared__ __hip_bfloat16 Bs[128 * 40];   // padded: reg-staged
  const int tid = threadIdx.x;
  const int l = tid & 63, w = tid >> 6;
  const int bm = blockIdx.y * 64, bn = blockIdx.x * 128;
  const int wr = w >> 1, wc = w & 1;
  const int lr = l & 15, kh = l >> 4;
  const int lrow = tid >> 2, lcol = (tid & 3) * 8;

  f32x4 acc[2][4];
  #pragma unroll
  for (int i = 0; i < 2; ++i)
    #pragma unroll
    for (int j = 0; j < 4; ++j)
      acc[i][j] = (f32x4){0.f, 0.f, 0.f, 0.f};

  for (int k0 = 0; k0 < K; k0 += 32) {
    // A: 64x32 bf16 = 1 glds chunk/thread (dest linear: elem off = tid*8)
    {
      const __hip_bfloat16* ga = A + (size_t)(bm + lrow) * K + k0 + lcol;
      __builtin_amdgcn_global_load_lds(
          (const __attribute__((address_space(1))) void*)ga,
          (__attribute__((address_space(3))) void*)&As[w * 512], 16, 0, 0);
    }
    // B: 128 rows fp32 -> bf16, 2 chunks/thread
    #pragma unroll
    for (int i = 0; i < 2; ++i) {
      const int row = i * 64 + lrow;
      const float* gb = Bw + (size_t)(bn + row) * K + k0 + lcol;
      float4 b0 = *(const float4*)gb, b1 = *(const float4*)(gb + 4);
      *(bf16x8*)&Bs[row * 40 + lcol] = pack8(b0, b1);
    }
    __syncthreads();

    bf16x8 af[2], bfr[4];
    #pragma unroll
    for (int f = 0; f < 2; ++f)
      af[f] = *(const bf16x8*)&As[(wr * 32 + f * 16 + lr) * 32 + kh * 8];
    #pragma unroll
    for (int f = 0; f < 4; ++f)
      bfr[f] = *(const bf16x8*)&Bs[(wc * 64 + f * 16 + lr) * 40 + kh * 8];
    #pragma unroll
    for (int fi = 0; fi < 2; ++fi)
      #pragma unroll
      for (int fj = 0; fj < 4; ++fj)
        acc[fi][fj] = __builtin_amdgcn_mfma_f32_16x16x32_bf16(af[fi], bfr[fj], acc[fi][fj], 0, 0, 0);
    __syncthreads();
  }

  #pragma unroll
  for (int fi = 0; fi < 2; ++fi)
    #pragma unroll
    for (int fj = 0; fj < 4; ++fj)
      #pragma unroll
      for (int rr = 0; rr < 4; ++rr) {
        const int m = bm + wr * 32 + fi * 16 + kh * 4 + rr;
        const int n = bn + wc * 64 + fj * 16 + lr;
        Cout[(size_t)m * N + n] = acc[fi][fj][rr] + bias[n];
      }
}

// ---------------- Local attention: 2 query-rows per block (R7 version) ------
// Block = 512 threads = one (b,h,row-pair rp). K/V rows 2rp-3..2rp+4 staged
// via global_load_lds, XOR swizzle x = ((tk>>1)^(tk>>6))&3 both sides.
// Thread (qr, c, s): slices dr {s-3, s+1}; combine via __shfl_xor(1/2).
__global__ __launch_bounds__(512) void local_attn(const _Float16* __restrict__ qkv,
                                                  const float* __restrict__ temp,
                                                  __hip_bfloat16* __restrict__ attn_out) {
  __shared__ _Float16 Ks[512 * 32];
  __shared__ _Float16 Vs[512 * 32];

  const int P = blockIdx.x;
  const int L = (P & 7) * 64 + (P >> 3);    // XCD-chunked remap (512 = 8*64)
  const int plane = L >> 5, rp = L & 31;
  const int b = plane >> 3, h = plane & 7;
  const int t = threadIdx.x;
  const int qr = t >> 8, c = (t >> 2) & 63, s = t & 3;
  const int r = rp * 2 + qr;

  const float scale = 0.17677669529663687f * temp[0];

  const _Float16* qplane = qkv + (size_t)(b * 8 + h) * (NTOK * HD);
  const _Float16* kplane = qkv + (size_t)(16 + b * 8 + h) * (NTOK * HD);
  const _Float16* vplane = qkv + (size_t)(32 + b * 8 + h) * (NTOK * HD);

  // ---- stage 8 grid rows of K/V (clamped), source pre-swizzled -------------
  {
    const int rbase = rp * 2 - 3;
    const int wbase = t & ~63;              // wave-uniform
    #pragma unroll
    for (int i = 0; i < 4; ++i) {
      const int id = i * 512 + t;
      const int drp = id >> 8;              // 0..7 (wave-uniform)
      const int tokloc = (id >> 2) & 63;
      const int jjp = id & 3;
      const int x = ((tokloc >> 1) ^ drp) & 3;
      const int jj = jjp ^ x;
      int row = rbase + drp;
      row = row < 0 ? 0 : (row > 63 ? 63 : row);
      const _Float16* src = kplane + (size_t)row * 2048 + tokloc * 32 + jj * 8;
      const _Float16* srv = vplane + (size_t)row * 2048 + tokloc * 32 + jj * 8;
      const int dbase = (i * 512 + wbase) * 8;
      __builtin_amdgcn_global_load_lds(
          (const __attribute__((address_space(1))) void*)src,
          (__attribute__((address_space(3))) void*)&Ks[dbase], 16, 0, 0);
      __builtin_amdgcn_global_load_lds(
          (const __attribute__((address_space(1))) void*)srv,
          (__attribute__((address_space(3))) void*)&Vs[dbase], 16, 0, 0);
    }
  }

  // ---- Q (own query) as fp16 pairs ----------------------------------------
  union { h8 v; h2v p[4]; } qu[4];
  {
    const _Float16* qrp_ = qplane + (size_t)(r * GRD + c) * HD;
    #pragma unroll
    for (int jj = 0; jj < 4; ++jj) qu[jj].v = *(const h8*)&qrp_[jj * 8];
  }
  __syncthreads();

  // ---- QK scores (slice s: dr = s-3 (i=0), s+1 (i=1, s<3 only)) -----------
  const char* KB = (const char*)Ks;
  const char* VB = (const char*)Vs;
  float sc[14];
  int bs[14];
  float mx = -INFINITY;
  const int ndr = (s < 3) ? 2 : 1;
  #pragma unroll
  for (int i = 0; i < 2; ++i) {
    const int dr = s - 3 + 4 * i;
    const int drp = dr + 3 + qr;            // staged row index 0..7
    const int rr = r + dr;
    const bool rowok = (i < ndr) && (rr >= 0) && (rr < GRD);
    #pragma unroll
    for (int dc = -3; dc <= 3; ++dc) {
      const int cc = c + dc;
      const bool ok = rowok && (cc >= 0) && (cc < GRD);
      int tk = drp * 64 + cc;
      tk = tk < 0 ? 0 : (tk > 511 ? 511 : tk);
      const int x = ((tk >> 1) ^ (tk >> 6)) & 3;
      const int sb = (tk << 6) ^ (x << 4);  // byte base, bits 4-5 swizzled
      bs[i * 7 + dc + 3] = sb;
      float dot = 0.f;
      #pragma unroll
      for (int jj = 0; jj < 4; ++jj) {
        union { h8 v; h2v p[4]; } kk;
        kk.v = *(const h8*)(KB + (sb ^ (jj << 4)));
        #pragma unroll
        for (int kx = 0; kx < 4; ++kx) {
#if HAVE_DOT2
          dot = __builtin_amdgcn_fdot2(kk.p[kx], qu[jj].p[kx], dot, false);
#else
          dot = fmaf((float)kk.p[kx][0], (float)qu[jj].p[kx][0], dot);
          dot = fmaf((float)kk.p[kx][1], (float)qu[jj].p[kx][1], dot);
#endif
        }
      }
      const float v = ok ? dot * scale : -INFINITY;
      sc[i * 7 + dc + 3] = v;
      mx = fmaxf(mx, v);
    }
  }

  // group max over the 4 slice-lanes (slice 3 i=0 is dr=0: always valid)
  mx = fmaxf(mx, __shfl_xor(mx, 1));
  mx = fmaxf(mx, __shfl_xor(mx, 2));

  float psum = 0.f;
  #pragma unroll
  for (int i = 0; i < 14; ++i) {
    float e = __expf(sc[i] - mx);   // exp(-inf - finite) = 0 for masked
    sc[i] = e;
    psum += e;
  }
  psum += __shfl_xor(psum, 1);
  psum += __shfl_xor(psum, 2);
  const float inv = 1.0f / psum;

  // ---- PV (branchless; masked p == 0, staged data finite) -----------------
  float o[HD];
  #pragma unroll
  for (int i = 0; i < HD; ++i) o[i] = 0.f;

  #pragma unroll
  for (int e = 0; e < 14; ++e) {
    const float p = sc[e];
    const int sb = bs[e];
    #pragma unroll
    for (int jj = 0; jj < 4; ++jj) {
      union { h8 v; h2v p2[4]; } vv;
      vv.v = *(const h8*)(VB + (sb ^ (jj << 4)));
      #pragma unroll
      for (int kx = 0; kx < 4; ++kx) {
        o[jj * 8 + kx * 2 + 0] = fmaf(p, (float)vv.p2[kx][0], o[jj * 8 + kx * 2 + 0]);
        o[jj * 8 + kx * 2 + 1] = fmaf(p, (float)vv.p2[kx][1], o[jj * 8 + kx * 2 + 1]);
      }
    }
  }

  // butterfly-combine partial O across the 4 slice-lanes
  #pragma unroll
  for (int d = 0; d < HD; ++d) {
    o[d] += __shfl_xor(o[d], 1);
    o[d] += __shfl_xor(o[d], 2);
  }

  // lane s writes dims [s*8, s*8+8) as bf16 (one 16 B store)
  union { uint4 u; unsigned short sh[8]; } pk;
  #pragma unroll
  for (int j = 0; j < 8; ++j) pk.sh[j] = f2b(o[s * 8 + j] * inv);
  __hip_bfloat16* dst = attn_out + ((size_t)(b * NTOK + r * GRD + c)) * DIM + h * HD + s * 8;
  *(uint4*)dst = pk.u;
}

extern "C" void kernel_launch(void* const* d_in, const int* in_sizes, int n_in,
                              void* d_out, int out_size, void* d_ws, size_t ws_size,
                              hipStream_t stream) {
  const float* x     = (const float*)d_in[0];
  const float* Wqkv  = (const float*)d_in[1];
  const float* Wproj = (const float*)d_in[2];
  const float* bproj = (const float*)d_in[3];
  const float* temp  = (const float*)d_in[4];
  float* out = (float*)d_out;

  // workspace layout (bytes):
  //   [0, 12582912)            qkv planar fp16: 48 planes of [4096][32]
  //   [25165824, 29360128)     attn_bf16 [8192][256]
  char* ws = (char*)d_ws;
  _Float16* qkv_f16       = (_Float16*)ws;
  __hip_bfloat16* attn_bf = (__hip_bfloat16*)(ws + 25165824);

  // 1) qkv = x @ Wqkv^T (fused fp32->bf16 cast) -> planar fp16
  {
    dim3 grid(3 * DIM / 128, MTOT / 64);    // (6, 128) = 768 blocks
    gemm_qkv<<<grid, 256, 0, stream>>>(x, Wqkv, qkv_f16);
  }
  // 2) local attention -> attn_bf [8192][256] bf16
  local_attn<<<BATCH * NHEAD * (GRD / 2), 512, 0, stream>>>(qkv_f16, temp, attn_bf);

  // 3) out = attn @ Wproj^T + bias (fused Wproj cast, fp32 out)
  {
    dim3 grid(DIM / 128, MTOT / 64);        // (2, 128) = 256 blocks
    gemm_proj<<<grid, 256, 0, stream>>>(attn_bf, Wproj, bproj, out);
  }
}

// Round 11
// 50.642 us; speedup vs baseline: 2.1744x; 1.0238x over previous
//
#include <hip/hip_runtime.h>
#include <hip/hip_bf16.h>
#include <math.h>

#define DIM   256
#define NHEAD 8
#define HD    32
#define NTOK  4096
#define GRD   64
#define BATCH 2
#define MTOT  (BATCH * NTOK)   // 8192
#define PLANE (NTOK * HD)      // 131072 elems per (sel,b,h) plane

typedef __attribute__((ext_vector_type(8))) short bf16x8;
typedef __attribute__((ext_vector_type(4))) float f32x4;

static __device__ __forceinline__ unsigned short f2b(float f) {
  __hip_bfloat16 h = __float2bfloat16(f);
  union { __hip_bfloat16 h; unsigned short u; } cv;
  cv.h = h;
  return cv.u;
}

static __device__ __forceinline__ unsigned cvtpk_bf16(float lo, float hi) {
  unsigned r;
  asm("v_cvt_pk_bf16_f32 %0, %1, %2" : "=v"(r) : "v"(lo), "v"(hi));
  return r;
}

static __device__ __forceinline__ bf16x8 pack8(float4 a0, float4 a1) {
  union { bf16x8 v; unsigned short u[8]; } o;
  o.u[0] = f2b(a0.x); o.u[1] = f2b(a0.y); o.u[2] = f2b(a0.z); o.u[3] = f2b(a0.w);
  o.u[4] = f2b(a1.x); o.u[5] = f2b(a1.y); o.u[6] = f2b(a1.z); o.u[7] = f2b(a1.w);
  return o.v;
}

#define GLDS16(SRC, DST) __builtin_amdgcn_global_load_lds( \
    (const __attribute__((address_space(1))) void*)(SRC),  \
    (__attribute__((address_space(3))) void*)(DST), 16, 0, 0)

// ---------------- GEMM1: qkv = x(fp32) @ Wqkv(fp32)^T -> bf16 planes --------
// 128x128 tile, grid (6,64). Q/K blocks (bx<4): scatter [tok][32] planes.
// V blocks (bx>=4): LDS-transpose epilogue -> V^T planes [32 d][4096 tok].
__global__ __launch_bounds__(256) void gemm_qkv(const float* __restrict__ A,
                                                const float* __restrict__ Bw,
                                                unsigned short* __restrict__ Cout) {
  const int K = 256;
  __shared__ __align__(16) char smem[34816];
  __hip_bfloat16* As = (__hip_bfloat16*)smem;            // [128*40]
  __hip_bfloat16* Bs = (__hip_bfloat16*)(smem + 10240);  // [128*40]
  const int tid = threadIdx.x;
  const int l = tid & 63, w = tid >> 6;
  const int bm = blockIdx.y * 128, bn = blockIdx.x * 128;
  const int wr = w >> 1, wc = w & 1;
  const int lr = l & 15, kh = l >> 4;
  const int lrow = l >> 2, lcol = (l & 3) * 8;

  f32x4 acc[4][4];
  #pragma unroll
  for (int i = 0; i < 4; ++i)
    #pragma unroll
    for (int j = 0; j < 4; ++j)
      acc[i][j] = (f32x4){0.f, 0.f, 0.f, 0.f};

  for (int k0 = 0; k0 < K; k0 += 32) {
    #pragma unroll
    for (int i = 0; i < 2; ++i) {
      const int r0 = (w * 2 + i) * 16;
      const float* ga = A  + (size_t)(bm + r0 + lrow) * K + k0 + lcol;
      const float* gb = Bw + (size_t)(bn + r0 + lrow) * K + k0 + lcol;
      float4 a0 = *(const float4*)ga, a1 = *(const float4*)(ga + 4);
      float4 b0 = *(const float4*)gb, b1 = *(const float4*)(gb + 4);
      *(bf16x8*)&As[(r0 + lrow) * 40 + lcol] = pack8(a0, a1);
      *(bf16x8*)&Bs[(r0 + lrow) * 40 + lcol] = pack8(b0, b1);
    }
    __syncthreads();

    bf16x8 af[4], bfr[4];
    #pragma unroll
    for (int f = 0; f < 4; ++f) {
      af[f]  = *(const bf16x8*)&As[(wr * 64 + f * 16 + lr) * 40 + kh * 8];
      bfr[f] = *(const bf16x8*)&Bs[(wc * 64 + f * 16 + lr) * 40 + kh * 8];
    }
    #pragma unroll
    for (int fi = 0; fi < 4; ++fi)
      #pragma unroll
      for (int fj = 0; fj < 4; ++fj)
        acc[fi][fj] = __builtin_amdgcn_mfma_f32_16x16x32_bf16(af[fi], bfr[fj], acc[fi][fj], 0, 0, 0);
    __syncthreads();
  }

  if (blockIdx.x < 4) {
    // Q/K planes: plane = sel*16 + bb*8 + hh, layout [tok][32]
    #pragma unroll
    for (int fi = 0; fi < 4; ++fi)
      #pragma unroll
      for (int fj = 0; fj < 4; ++fj)
        #pragma unroll
        for (int rr = 0; rr < 4; ++rr) {
          const int m = bm + wr * 64 + fi * 16 + kh * 4 + rr;
          const int n = bn + wc * 64 + fj * 16 + lr;
          const int sel = n >> 8, rem = n & 255;
          const int hh = rem >> 5, d = rem & 31;
          const int bb = m >> 12, tok = m & 4095;
          Cout[(size_t)(sel * 16 + bb * 8 + hh) * PLANE + tok * 32 + d] =
              f2b(acc[fi][fj][rr]);
        }
  } else {
    // V blocks: transpose through LDS, write V^T [d][tok] coalesced.
    unsigned short* Ts = (unsigned short*)smem;   // [128][136]
    #pragma unroll
    for (int fi = 0; fi < 4; ++fi)
      #pragma unroll
      for (int fj = 0; fj < 4; ++fj)
        #pragma unroll
        for (int rr = 0; rr < 4; ++rr) {
          const int tokl = wr * 64 + fi * 16 + kh * 4 + rr;
          const int dl   = wc * 64 + fj * 16 + lr;
          Ts[tokl * 136 + dl] = f2b(acc[fi][fj][rr]);
        }
    __syncthreads();
    const int dl = tid >> 1, th = (tid & 1) * 64;
    const int dg = (bn - 512) + dl;          // 0..255
    const int hh = dg >> 5, dd = dg & 31;
    const int bb = bm >> 12, tokb = bm & 4095;
    unsigned short* vt = Cout + (size_t)(32 + bb * 8 + hh) * PLANE + dd * 4096 + tokb + th;
    #pragma unroll
    for (int j = 0; j < 8; ++j) {
      union { bf16x8 v; unsigned short u[8]; } o;
      #pragma unroll
      for (int e = 0; e < 8; ++e)
        o.u[e] = Ts[(th + j * 8 + e) * 136 + dl];
      *(bf16x8*)(vt + j * 8) = o.v;
    }
  }
}

// ---------------- GEMM2: out = attn(bf16) @ Wproj(fp32)^T + bias (fp32) -----
__global__ __launch_bounds__(256) void gemm_proj(const __hip_bfloat16* __restrict__ A,
                                                 const float* __restrict__ Bw,
                                                 const float* __restrict__ bias,
                                                 float* __restrict__ Cout) {
  const int K = 256, N = 256;
  __shared__ __hip_bfloat16 As[128 * 32];   // linear: global_load_lds dest
  __shared__ __hip_bfloat16 Bs[128 * 40];   // padded: reg-staged
  const int tid = threadIdx.x;
  const int l = tid & 63, w = tid >> 6;
  const int bm = blockIdx.y * 128, bn = blockIdx.x * 128;
  const int wr = w >> 1, wc = w & 1;
  const int lr = l & 15, kh = l >> 4;
  const int lrow = l >> 2, lcol = (l & 3) * 8;

  f32x4 acc[4][4];
  #pragma unroll
  for (int i = 0; i < 4; ++i)
    #pragma unroll
    for (int j = 0; j < 4; ++j)
      acc[i][j] = (f32x4){0.f, 0.f, 0.f, 0.f};

  for (int k0 = 0; k0 < K; k0 += 32) {
    #pragma unroll
    for (int i = 0; i < 2; ++i) {
      const int r0 = (w * 2 + i) * 16;
      const __hip_bfloat16* ga = A + (size_t)(bm + r0 + lrow) * K + k0 + lcol;
      GLDS16(ga, &As[r0 * 32]);
      const float* gb = Bw + (size_t)(bn + r0 + lrow) * K + k0 + lcol;
      float4 b0 = *(const float4*)gb, b1 = *(const float4*)(gb + 4);
      *(bf16x8*)&Bs[(r0 + lrow) * 40 + lcol] = pack8(b0, b1);
    }
    __syncthreads();

    bf16x8 af[4], bfr[4];
    #pragma unroll
    for (int f = 0; f < 4; ++f) {
      af[f]  = *(const bf16x8*)&As[(wr * 64 + f * 16 + lr) * 32 + kh * 8];
      bfr[f] = *(const bf16x8*)&Bs[(wc * 64 + f * 16 + lr) * 40 + kh * 8];
    }
    #pragma unroll
    for (int fi = 0; fi < 4; ++fi)
      #pragma unroll
      for (int fj = 0; fj < 4; ++fj)
        acc[fi][fj] = __builtin_amdgcn_mfma_f32_16x16x32_bf16(af[fi], bfr[fj], acc[fi][fj], 0, 0, 0);
    __syncthreads();
  }

  #pragma unroll
  for (int fi = 0; fi < 4; ++fi)
    #pragma unroll
    for (int fj = 0; fj < 4; ++fj)
      #pragma unroll
      for (int rr = 0; rr < 4; ++rr) {
        const int m = bm + wr * 64 + fi * 16 + kh * 4 + rr;
        const int n = bn + wc * 64 + fj * 16 + lr;
        Cout[(size_t)m * N + n] = acc[fi][fj][rr] + bias[n];
      }
}

// ---------------- MFMA flash-band local attention ---------------------------
// Block = 4 waves x 16 queries = one (b,h,grid-row r). Dense 64q x 448key band
// via mfma_f32_16x16x32_bf16 with online softmax; mask applied on S^T.
// Layouts (q = lane&15 everywhere):
//   S^T = mfma(K_frag, Q_frag): lane holds S^T[key=kt*16+sg*4+reg][q]
//   O^T = mfma(Vt_frag, P_frag): lane holds O^T[d=dt*16+sg*4+reg][q]
// K LDS [tok][32], 16B-chunk swizzle ^((tok>>1)&3); V^T LDS [32][512] pitch
// 1024B, chunk swizzle ^(d&7). Both staged via global_load_lds with the
// inverse swizzle pre-applied to the global source address.
__global__ __launch_bounds__(256) void local_attn_mfma(
    const unsigned short* __restrict__ qkv, const float* __restrict__ temp,
    unsigned short* __restrict__ attn_out) {
  __shared__ __align__(16) unsigned short Ks[448 * 32];   // 28672 B
  __shared__ __align__(16) unsigned short Vt[32 * 512];   // 32768 B

  const int P = blockIdx.x;
  const int L = (P & 7) * 128 + (P >> 3);   // XCD-chunked remap (1024 = 8*128)
  const int b = L >> 9, h = (L >> 6) & 7, r = L & 63;
  const int tid = threadIdx.x;
  const int l = tid & 63, wv = tid >> 6;
  const int q15 = l & 15, sg = l >> 4;

  const float scale = 0.17677669529663687f * temp[0];

  const unsigned short* qplane  = qkv + (size_t)(b * 8 + h) * PLANE;
  const unsigned short* kplane  = qplane + (size_t)16 * PLANE;
  const unsigned short* vtplane = qplane + (size_t)32 * PLANE;

  // ---- stage K: 448 band-tokens x 64B rows (1792 16B chunks) ---------------
  #pragma unroll
  for (int i = 0; i < 7; ++i) {
    const int ch = i * 256 + tid;
    const int tok = ch >> 2, jjp = ch & 3;
    const int ri = tok >> 6, kloc = tok & 63;
    int rr = r - 3 + ri; rr = rr < 0 ? 0 : (rr > 63 ? 63 : rr);
    const int jl = jjp ^ ((tok >> 1) & 3);
    const unsigned short* src = kplane + (size_t)(rr * 64 + kloc) * 32 + jl * 8;
    GLDS16(src, &Ks[(i * 256 + (tid & ~63)) * 8]);
  }
  // ---- stage V^T: 32 d-rows x 512 tokens (rows r-3..r+4 clamped) -----------
  #pragma unroll
  for (int i = 0; i < 8; ++i) {
    const int ch = i * 256 + tid;
    const int d = ch >> 6, chp = ch & 63;
    const int chl = chp ^ (d & 7);
    const int ri = chl >> 3, part = chl & 7;
    int rr = r - 3 + ri; rr = rr < 0 ? 0 : (rr > 63 ? 63 : rr);
    const unsigned short* src = vtplane + (size_t)d * 4096 + rr * 64 + part * 8;
    GLDS16(src, &Vt[(i * 256 + (tid & ~63)) * 8]);
  }

  // ---- Q fragment (B-operand style): Q[q15][sg*8..+8] ----------------------
  const bf16x8 qf = *(const bf16x8*)(qplane + (size_t)(r * 64 + wv * 16 + q15) * 32 + sg * 8);

  __syncthreads();

  const int qcol = wv * 16 + q15;
  float m_run = -INFINITY, l_run = 0.f;
  f32x4 Od[2];
  Od[0] = (f32x4){0.f, 0.f, 0.f, 0.f};
  Od[1] = (f32x4){0.f, 0.f, 0.f, 0.f};
  const f32x4 zf = {0.f, 0.f, 0.f, 0.f};
  const int laA = ((l >> 4) & 1) * 32 + q15;   // source lane for P-frag low keys
  const int laB = laA + 16;
  const bool hiG = (l & 32) != 0;              // group>=2 -> use kt 2h+1

  #pragma unroll
  for (int c = 0; c < 7; ++c) {
    const int rr_c = r - 3 + c;
    if (rr_c >= 0 && rr_c <= 63) {
      // ---- QK^T: 4 S^T tiles -----------------------------------------------
      f32x4 st[4];
      #pragma unroll
      for (int kt = 0; kt < 4; ++kt) {
        const int tok = c * 64 + kt * 16 + q15;
        const bf16x8 kf = *(const bf16x8*)((const char*)Ks + tok * 64 +
                                           ((sg ^ ((tok >> 1) & 3)) << 4));
        st[kt] = __builtin_amdgcn_mfma_f32_16x16x32_bf16(kf, qf, zf, 0, 0, 0);
      }
      // ---- mask + scale + chunk max ---------------------------------------
      float mc = -INFINITY;
      #pragma unroll
      for (int kt = 0; kt < 4; ++kt)
        #pragma unroll
        for (int rg = 0; rg < 4; ++rg) {
          const int keyloc = kt * 16 + sg * 4 + rg;
          const bool ok = (unsigned)(keyloc - qcol + 3) <= 6u;
          const float v = ok ? st[kt][rg] * scale : -INFINITY;
          st[kt][rg] = v;
          mc = fmaxf(mc, v);
        }
      mc = fmaxf(mc, __shfl_xor(mc, 16));
      mc = fmaxf(mc, __shfl_xor(mc, 32));
      const float mnew = fmaxf(m_run, mc);
      const float alpha = __expf(m_run - mnew);   // 0 on first chunk
      float lc = 0.f;
      #pragma unroll
      for (int kt = 0; kt < 4; ++kt)
        #pragma unroll
        for (int rg = 0; rg < 4; ++rg) {
          const float e = __expf(st[kt][rg] - mnew);   // masked -> 0
          st[kt][rg] = e;
          lc += e;
        }
      lc += __shfl_xor(lc, 16);
      lc += __shfl_xor(lc, 32);
      l_run = l_run * alpha + lc;
      m_run = mnew;
      Od[0] *= alpha;
      Od[1] *= alpha;

      // ---- pack p to bf16 pairs, exchange into P B-frags, PV --------------
      unsigned pkw[8];
      #pragma unroll
      for (int kt = 0; kt < 4; ++kt) {
        pkw[kt * 2 + 0] = cvtpk_bf16(st[kt][0], st[kt][1]);
        pkw[kt * 2 + 1] = cvtpk_bf16(st[kt][2], st[kt][3]);
      }
      #pragma unroll
      for (int hf = 0; hf < 2; ++hf) {
        unsigned wA[2], wB[2];
        #pragma unroll
        for (int w2 = 0; w2 < 2; ++w2) {
          const unsigned a0 = (unsigned)__shfl((int)pkw[(2 * hf) * 2 + w2], laA);
          const unsigned a1 = (unsigned)__shfl((int)pkw[(2 * hf + 1) * 2 + w2], laA);
          wA[w2] = hiG ? a1 : a0;
          const unsigned b0 = (unsigned)__shfl((int)pkw[(2 * hf) * 2 + w2], laB);
          const unsigned b1 = (unsigned)__shfl((int)pkw[(2 * hf + 1) * 2 + w2], laB);
          wB[w2] = hiG ? b1 : b0;
        }
        union { unsigned u[4]; bf16x8 v; } pf;
        pf.u[0] = wA[0]; pf.u[1] = wA[1]; pf.u[2] = wB[0]; pf.u[3] = wB[1];
        #pragma unroll
        for (int dt = 0; dt < 2; ++dt) {
          const int d = dt * 16 + q15;
          const int chl = c * 8 + hf * 4 + sg;
          const bf16x8 vf = *(const bf16x8*)((const char*)Vt + d * 1024 +
                                             ((chl ^ (d & 7)) << 4));
          Od[dt] = __builtin_amdgcn_mfma_f32_16x16x32_bf16(vf, pf.v, Od[dt], 0, 0, 0);
        }
      }
    }
  }

  // ---- normalize + store O^T (lane: d = dt*16+sg*4+rg, q = q15) ------------
  const float invl = 1.0f / l_run;
  #pragma unroll
  for (int dt = 0; dt < 2; ++dt) {
    const unsigned w0 = cvtpk_bf16(Od[dt][0] * invl, Od[dt][1] * invl);
    const unsigned w1 = cvtpk_bf16(Od[dt][2] * invl, Od[dt][3] * invl);
    unsigned short* dst = attn_out + (size_t)(b * 4096 + r * 64 + qcol) * 256 +
                          h * 32 + dt * 16 + sg * 4;
    uint2 uu; uu.x = w0; uu.y = w1;
    *(uint2*)dst = uu;
  }
}

extern "C" void kernel_launch(void* const* d_in, const int* in_sizes, int n_in,
                              void* d_out, int out_size, void* d_ws, size_t ws_size,
                              hipStream_t stream) {
  const float* x     = (const float*)d_in[0];
  const float* Wqkv  = (const float*)d_in[1];
  const float* Wproj = (const float*)d_in[2];
  const float* bproj = (const float*)d_in[3];
  const float* temp  = (const float*)d_in[4];
  float* out = (float*)d_out;

  // workspace layout (bytes):
  //   [0, 12582912)            qkv bf16 planes: 48 x 131072 elems
  //                            (Q/K planes [tok][32]; V planes transposed [32][4096])
  //   [25165824, 29360128)     attn_bf16 [8192][256]
  char* ws = (char*)d_ws;
  unsigned short* qkv_bf  = (unsigned short*)ws;
  __hip_bfloat16* attn_bf = (__hip_bfloat16*)(ws + 25165824);

  // 1) qkv = x @ Wqkv^T (fused fp32->bf16), Q/K planar + V transposed
  {
    dim3 grid(3 * DIM / 128, MTOT / 128);   // (6, 64)
    gemm_qkv<<<grid, 256, 0, stream>>>(x, Wqkv, qkv_bf);
  }
  // 2) MFMA flash-band attention -> attn_bf [8192][256]
  local_attn_mfma<<<BATCH * NHEAD * GRD, 256, 0, stream>>>(qkv_bf, temp,
                                                           (unsigned short*)attn_bf);
  // 3) out = attn @ Wproj^T + bias
  {
    dim3 grid(DIM / 128, MTOT / 128);       // (2, 64)
    gemm_proj<<<grid, 256, 0, stream>>>(attn_bf, Wproj, bproj, out);
  }
}

// Round 12
// 45.915 us; speedup vs baseline: 2.3982x; 1.1029x over previous
//
#include <hip/hip_runtime.h>
#include <hip/hip_bf16.h>
#include <math.h>

#define DIM   256
#define NHEAD 8
#define HD    32
#define NTOK  4096
#define GRD   64
#define BATCH 2
#define MTOT  (BATCH * NTOK)   // 8192
#define PLANE (NTOK * HD)      // 131072 elems per (sel,b,h) plane

typedef __attribute__((ext_vector_type(8))) short bf16x8;
typedef __attribute__((ext_vector_type(4))) float f32x4;

static __device__ __forceinline__ unsigned short f2b(float f) {
  __hip_bfloat16 h = __float2bfloat16(f);
  union { __hip_bfloat16 h; unsigned short u; } cv;
  cv.h = h;
  return cv.u;
}

static __device__ __forceinline__ unsigned cvtpk_bf16(float lo, float hi) {
  unsigned r;
  asm("v_cvt_pk_bf16_f32 %0, %1, %2" : "=v"(r) : "v"(lo), "v"(hi));
  return r;
}

static __device__ __forceinline__ bf16x8 pack8(float4 a0, float4 a1) {
  union { bf16x8 v; unsigned short u[8]; } o;
  o.u[0] = f2b(a0.x); o.u[1] = f2b(a0.y); o.u[2] = f2b(a0.z); o.u[3] = f2b(a0.w);
  o.u[4] = f2b(a1.x); o.u[5] = f2b(a1.y); o.u[6] = f2b(a1.z); o.u[7] = f2b(a1.w);
  return o.v;
}

#define GLDS16(SRC, DST) __builtin_amdgcn_global_load_lds( \
    (const __attribute__((address_space(1))) void*)(SRC),  \
    (__attribute__((address_space(3))) void*)(DST), 16, 0, 0)

// ---------------- GEMM1: qkv = x(fp32) @ Wqkv(fp32)^T -> bf16 planes --------
// 128x128 tile, grid (6,64). Q/K blocks (bx<4): scatter [tok][32] planes.
// V blocks (bx>=4): LDS-transpose epilogue -> V^T planes [32 d][4096 tok].
__global__ __launch_bounds__(256) void gemm_qkv(const float* __restrict__ A,
                                                const float* __restrict__ Bw,
                                                unsigned short* __restrict__ Cout) {
  const int K = 256;
  __shared__ __align__(16) char smem[34816];
  __hip_bfloat16* As = (__hip_bfloat16*)smem;            // [128*40]
  __hip_bfloat16* Bs = (__hip_bfloat16*)(smem + 10240);  // [128*40]
  const int tid = threadIdx.x;
  const int l = tid & 63, w = tid >> 6;
  const int bm = blockIdx.y * 128, bn = blockIdx.x * 128;
  const int wr = w >> 1, wc = w & 1;
  const int lr = l & 15, kh = l >> 4;
  const int lrow = l >> 2, lcol = (l & 3) * 8;

  f32x4 acc[4][4];
  #pragma unroll
  for (int i = 0; i < 4; ++i)
    #pragma unroll
    for (int j = 0; j < 4; ++j)
      acc[i][j] = (f32x4){0.f, 0.f, 0.f, 0.f};

  for (int k0 = 0; k0 < K; k0 += 32) {
    #pragma unroll
    for (int i = 0; i < 2; ++i) {
      const int r0 = (w * 2 + i) * 16;
      const float* ga = A  + (size_t)(bm + r0 + lrow) * K + k0 + lcol;
      const float* gb = Bw + (size_t)(bn + r0 + lrow) * K + k0 + lcol;
      float4 a0 = *(const float4*)ga, a1 = *(const float4*)(ga + 4);
      float4 b0 = *(const float4*)gb, b1 = *(const float4*)(gb + 4);
      *(bf16x8*)&As[(r0 + lrow) * 40 + lcol] = pack8(a0, a1);
      *(bf16x8*)&Bs[(r0 + lrow) * 40 + lcol] = pack8(b0, b1);
    }
    __syncthreads();

    bf16x8 af[4], bfr[4];
    #pragma unroll
    for (int f = 0; f < 4; ++f) {
      af[f]  = *(const bf16x8*)&As[(wr * 64 + f * 16 + lr) * 40 + kh * 8];
      bfr[f] = *(const bf16x8*)&Bs[(wc * 64 + f * 16 + lr) * 40 + kh * 8];
    }
    #pragma unroll
    for (int fi = 0; fi < 4; ++fi)
      #pragma unroll
      for (int fj = 0; fj < 4; ++fj)
        acc[fi][fj] = __builtin_amdgcn_mfma_f32_16x16x32_bf16(af[fi], bfr[fj], acc[fi][fj], 0, 0, 0);
    __syncthreads();
  }

  if (blockIdx.x < 4) {
    // Q/K planes: plane = sel*16 + bb*8 + hh, layout [tok][32]
    #pragma unroll
    for (int fi = 0; fi < 4; ++fi)
      #pragma unroll
      for (int fj = 0; fj < 4; ++fj)
        #pragma unroll
        for (int rr = 0; rr < 4; ++rr) {
          const int m = bm + wr * 64 + fi * 16 + kh * 4 + rr;
          const int n = bn + wc * 64 + fj * 16 + lr;
          const int sel = n >> 8, rem = n & 255;
          const int hh = rem >> 5, d = rem & 31;
          const int bb = m >> 12, tok = m & 4095;
          Cout[(size_t)(sel * 16 + bb * 8 + hh) * PLANE + tok * 32 + d] =
              f2b(acc[fi][fj][rr]);
        }
  } else {
    // V blocks: transpose through LDS, write V^T [d][tok] coalesced.
    unsigned short* Ts = (unsigned short*)smem;   // [128][136]
    #pragma unroll
    for (int fi = 0; fi < 4; ++fi)
      #pragma unroll
      for (int fj = 0; fj < 4; ++fj)
        #pragma unroll
        for (int rr = 0; rr < 4; ++rr) {
          const int tokl = wr * 64 + fi * 16 + kh * 4 + rr;
          const int dl   = wc * 64 + fj * 16 + lr;
          Ts[tokl * 136 + dl] = f2b(acc[fi][fj][rr]);
        }
    __syncthreads();
    const int dl = tid >> 1, th = (tid & 1) * 64;
    const int dg = (bn - 512) + dl;          // 0..255
    const int hh = dg >> 5, dd = dg & 31;
    const int bb = bm >> 12, tokb = bm & 4095;
    unsigned short* vt = Cout + (size_t)(32 + bb * 8 + hh) * PLANE + dd * 4096 + tokb + th;
    #pragma unroll
    for (int j = 0; j < 8; ++j) {
      union { bf16x8 v; unsigned short u[8]; } o;
      #pragma unroll
      for (int e = 0; e < 8; ++e)
        o.u[e] = Ts[(th + j * 8 + e) * 136 + dl];
      *(bf16x8*)(vt + j * 8) = o.v;
    }
  }
}

// ---------------- GEMM2: out = attn(bf16) @ Wproj(fp32)^T + bias (fp32) -----
// 64x128 tile -> grid (2, 128) = 256 blocks (full GPU; R7-measured config).
__global__ __launch_bounds__(256) void gemm_proj(const __hip_bfloat16* __restrict__ A,
                                                 const float* __restrict__ Bw,
                                                 const float* __restrict__ bias,
                                                 float* __restrict__ Cout) {
  const int K = 256, N = 256;
  __shared__ __hip_bfloat16 As[64 * 32];    // linear: global_load_lds dest
  __shared__ __hip_bfloat16 Bs[128 * 40];   // padded: reg-staged
  const int tid = threadIdx.x;
  const int l = tid & 63, w = tid >> 6;
  const int bm = blockIdx.y * 64, bn = blockIdx.x * 128;
  const int wr = w >> 1, wc = w & 1;
  const int lr = l & 15, kh = l >> 4;
  const int lrow = tid >> 2, lcol = (tid & 3) * 8;

  f32x4 acc[2][4];
  #pragma unroll
  for (int i = 0; i < 2; ++i)
    #pragma unroll
    for (int j = 0; j < 4; ++j)
      acc[i][j] = (f32x4){0.f, 0.f, 0.f, 0.f};

  for (int k0 = 0; k0 < K; k0 += 32) {
    {
      const __hip_bfloat16* ga = A + (size_t)(bm + lrow) * K + k0 + lcol;
      GLDS16(ga, &As[w * 512]);
    }
    #pragma unroll
    for (int i = 0; i < 2; ++i) {
      const int row = i * 64 + lrow;
      const float* gb = Bw + (size_t)(bn + row) * K + k0 + lcol;
      float4 b0 = *(const float4*)gb, b1 = *(const float4*)(gb + 4);
      *(bf16x8*)&Bs[row * 40 + lcol] = pack8(b0, b1);
    }
    __syncthreads();

    bf16x8 af[2], bfr[4];
    #pragma unroll
    for (int f = 0; f < 2; ++f)
      af[f] = *(const bf16x8*)&As[(wr * 32 + f * 16 + lr) * 32 + kh * 8];
    #pragma unroll
    for (int f = 0; f < 4; ++f)
      bfr[f] = *(const bf16x8*)&Bs[(wc * 64 + f * 16 + lr) * 40 + kh * 8];
    #pragma unroll
    for (int fi = 0; fi < 2; ++fi)
      #pragma unroll
      for (int fj = 0; fj < 4; ++fj)
        acc[fi][fj] = __builtin_amdgcn_mfma_f32_16x16x32_bf16(af[fi], bfr[fj], acc[fi][fj], 0, 0, 0);
    __syncthreads();
  }

  #pragma unroll
  for (int fi = 0; fi < 2; ++fi)
    #pragma unroll
    for (int fj = 0; fj < 4; ++fj)
      #pragma unroll
      for (int rr = 0; rr < 4; ++rr) {
        const int m = bm + wr * 32 + fi * 16 + kh * 4 + rr;
        const int n = bn + wc * 64 + fj * 16 + lr;
        Cout[(size_t)m * N + n] = acc[fi][fj][rr] + bias[n];
      }
}

// ---------------- MFMA flash-band attention, 2 query-rows per block ---------
// Block = 8 waves x 16 queries = one (b,h,row-pair rp): query rows 2rp,2rp+1.
// Wave wv: qr = wv>>2 (row), wq = wv&3 (16-query group). Stage K/V for grid
// rows 2rp-3..2rp+4 (512 toks): Ks [512 tok][32] (chunk swz ^((tok>>1)&3)),
// Vt [32 d][512 tok] pitch 1024B (chunk swz ^(d&7)); inverse swizzle applied
// to the global source (both-sides rule). 64 KB LDS -> 2 blocks/CU, 512
// blocks = 1 full-resident round, 4 waves/SIMD.
__global__ __launch_bounds__(512, 4) void local_attn_mfma(
    const unsigned short* __restrict__ qkv, const float* __restrict__ temp,
    unsigned short* __restrict__ attn_out) {
  __shared__ __align__(16) unsigned short Ks[512 * 32];   // 32768 B
  __shared__ __align__(16) unsigned short Vt[32 * 512];   // 32768 B

  const int P = blockIdx.x;
  const int L = (P & 7) * 64 + (P >> 3);    // XCD-chunked remap (512 = 8*64)
  const int plane = L >> 5, rp = L & 31;
  const int b = plane >> 3, h = plane & 7;
  const int tid = threadIdx.x;
  const int l = tid & 63, wv = tid >> 6;
  const int qr = wv >> 2, wq = wv & 3;
  const int q15 = l & 15, sg = l >> 4;
  const int r = rp * 2 + qr;                // this wave's query grid-row

  const float scale = 0.17677669529663687f * temp[0];

  const unsigned short* qplane  = qkv + (size_t)(b * 8 + h) * PLANE;
  const unsigned short* kplane  = qplane + (size_t)16 * PLANE;
  const unsigned short* vtplane = qplane + (size_t)32 * PLANE;

  const int rbase = rp * 2 - 3;

  // ---- stage K: 512 band-tokens x 64B rows (2048 16B chunks) ---------------
  #pragma unroll
  for (int i = 0; i < 4; ++i) {
    const int ch = i * 512 + tid;
    const int tok = ch >> 2, jjp = ch & 3;
    const int ri = tok >> 6, kloc = tok & 63;
    int row = rbase + ri; row = row < 0 ? 0 : (row > 63 ? 63 : row);
    const int jl = jjp ^ ((tok >> 1) & 3);
    const unsigned short* src = kplane + (size_t)(row * 64 + kloc) * 32 + jl * 8;
    GLDS16(src, &Ks[(i * 512 + (tid & ~63)) * 8]);
  }
  // ---- stage V^T: 32 d-rows x 512 tokens (2048 16B chunks) -----------------
  #pragma unroll
  for (int i = 0; i < 4; ++i) {
    const int ch = i * 512 + tid;
    const int d = ch >> 6, chp = ch & 63;
    const int chl = chp ^ (d & 7);
    const int ri = chl >> 3, part = chl & 7;
    int row = rbase + ri; row = row < 0 ? 0 : (row > 63 ? 63 : row);
    const unsigned short* src = vtplane + (size_t)d * 4096 + row * 64 + part * 8;
    GLDS16(src, &Vt[(i * 512 + (tid & ~63)) * 8]);
  }

  // ---- Q fragment (B-operand style): Q[q15][sg*8..+8] ----------------------
  const bf16x8 qf = *(const bf16x8*)(qplane + (size_t)(r * 64 + wq * 16 + q15) * 32 + sg * 8);

  __syncthreads();

  const int qcol = wq * 16 + q15;
  float m_run = -INFINITY, l_run = 0.f;
  f32x4 Od[2];
  Od[0] = (f32x4){0.f, 0.f, 0.f, 0.f};
  Od[1] = (f32x4){0.f, 0.f, 0.f, 0.f};
  const f32x4 zf = {0.f, 0.f, 0.f, 0.f};
  const int laA = ((l >> 4) & 1) * 32 + q15;   // source lane for P-frag low keys
  const int laB = laA + 16;
  const bool hiG = (l & 32) != 0;              // group>=2 -> use kt 2h+1

  #pragma unroll
  for (int c = 0; c < 7; ++c) {
    const int rr_c = r - 3 + c;                // wave-uniform
    if (rr_c >= 0 && rr_c <= 63) {
      const int bri = c + qr;                  // staged band-row index 0..7
      // ---- QK^T: 4 S^T tiles ----------------------------------------------
      f32x4 st[4];
      #pragma unroll
      for (int kt = 0; kt < 4; ++kt) {
        const int tok = bri * 64 + kt * 16 + q15;
        const bf16x8 kf = *(const bf16x8*)((const char*)Ks + tok * 64 +
                                           ((sg ^ ((tok >> 1) & 3)) << 4));
        st[kt] = __builtin_amdgcn_mfma_f32_16x16x32_bf16(kf, qf, zf, 0, 0, 0);
      }
      // ---- mask + scale + chunk max ---------------------------------------
      float mc = -INFINITY;
      #pragma unroll
      for (int kt = 0; kt < 4; ++kt)
        #pragma unroll
        for (int rg = 0; rg < 4; ++rg) {
          const int keyloc = kt * 16 + sg * 4 + rg;
          const bool ok = (unsigned)(keyloc - qcol + 3) <= 6u;
          const float v = ok ? st[kt][rg] * scale : -INFINITY;
          st[kt][rg] = v;
          mc = fmaxf(mc, v);
        }
      mc = fmaxf(mc, __shfl_xor(mc, 16));
      mc = fmaxf(mc, __shfl_xor(mc, 32));
      const float mnew = fmaxf(m_run, mc);
      const float alpha = __expf(m_run - mnew);   // 0 on first chunk
      float lc = 0.f;
      #pragma unroll
      for (int kt = 0; kt < 4; ++kt)
        #pragma unroll
        for (int rg = 0; rg < 4; ++rg) {
          const float e = __expf(st[kt][rg] - mnew);   // masked -> 0
          st[kt][rg] = e;
          lc += e;
        }
      lc += __shfl_xor(lc, 16);
      lc += __shfl_xor(lc, 32);
      l_run = l_run * alpha + lc;
      m_run = mnew;
      Od[0] *= alpha;
      Od[1] *= alpha;

      // ---- pack p to bf16 pairs, exchange into P B-frags, PV --------------
      unsigned pkw[8];
      #pragma unroll
      for (int kt = 0; kt < 4; ++kt) {
        pkw[kt * 2 + 0] = cvtpk_bf16(st[kt][0], st[kt][1]);
        pkw[kt * 2 + 1] = cvtpk_bf16(st[kt][2], st[kt][3]);
      }
      #pragma unroll
      for (int hf = 0; hf < 2; ++hf) {
        unsigned wA[2], wB[2];
        #pragma unroll
        for (int w2 = 0; w2 < 2; ++w2) {
          const unsigned a0 = (unsigned)__shfl((int)pkw[(2 * hf) * 2 + w2], laA);
          const unsigned a1 = (unsigned)__shfl((int)pkw[(2 * hf + 1) * 2 + w2], laA);
          wA[w2] = hiG ? a1 : a0;
          const unsigned b0 = (unsigned)__shfl((int)pkw[(2 * hf) * 2 + w2], laB);
          const unsigned b1 = (unsigned)__shfl((int)pkw[(2 * hf + 1) * 2 + w2], laB);
          wB[w2] = hiG ? b1 : b0;
        }
        union { unsigned u[4]; bf16x8 v; } pf;
        pf.u[0] = wA[0]; pf.u[1] = wA[1]; pf.u[2] = wB[0]; pf.u[3] = wB[1];
        #pragma unroll
        for (int dt = 0; dt < 2; ++dt) {
          const int d = dt * 16 + q15;
          const int chl = bri * 8 + hf * 4 + sg;
          const bf16x8 vf = *(const bf16x8*)((const char*)Vt + d * 1024 +
                                             ((chl ^ (d & 7)) << 4));
          Od[dt] = __builtin_amdgcn_mfma_f32_16x16x32_bf16(vf, pf.v, Od[dt], 0, 0, 0);
        }
      }
    }
  }

  // ---- normalize + store O^T (lane: d = dt*16+sg*4+rg, q = q15) ------------
  const float invl = 1.0f / l_run;
  #pragma unroll
  for (int dt = 0; dt < 2; ++dt) {
    const unsigned w0 = cvtpk_bf16(Od[dt][0] * invl, Od[dt][1] * invl);
    const unsigned w1 = cvtpk_bf16(Od[dt][2] * invl, Od[dt][3] * invl);
    unsigned short* dst = attn_out + (size_t)(b * 4096 + r * 64 + qcol) * 256 +
                          h * 32 + dt * 16 + sg * 4;
    uint2 uu; uu.x = w0; uu.y = w1;
    *(uint2*)dst = uu;
  }
}

extern "C" void kernel_launch(void* const* d_in, const int* in_sizes, int n_in,
                              void* d_out, int out_size, void* d_ws, size_t ws_size,
                              hipStream_t stream) {
  const float* x     = (const float*)d_in[0];
  const float* Wqkv  = (const float*)d_in[1];
  const float* Wproj = (const float*)d_in[2];
  const float* bproj = (const float*)d_in[3];
  const float* temp  = (const float*)d_in[4];
  float* out = (float*)d_out;

  // workspace layout (bytes):
  //   [0, 12582912)            qkv bf16 planes: 48 x 131072 elems
  //                            (Q/K planes [tok][32]; V planes transposed [32][4096])
  //   [25165824, 29360128)     attn_bf16 [8192][256]
  char* ws = (char*)d_ws;
  unsigned short* qkv_bf  = (unsigned short*)ws;
  __hip_bfloat16* attn_bf = (__hip_bfloat16*)(ws + 25165824);

  // 1) qkv = x @ Wqkv^T (fused fp32->bf16), Q/K planar + V transposed
  {
    dim3 grid(3 * DIM / 128, MTOT / 128);   // (6, 64)
    gemm_qkv<<<grid, 256, 0, stream>>>(x, Wqkv, qkv_bf);
  }
  // 2) MFMA flash-band attention (2 query-rows/block) -> attn_bf
  local_attn_mfma<<<BATCH * NHEAD * (GRD / 2), 512, 0, stream>>>(
      qkv_bf, temp, (unsigned short*)attn_bf);
  // 3) out = attn @ Wproj^T + bias
  {
    dim3 grid(DIM / 128, MTOT / 64);        // (2, 128) = 256 blocks
    gemm_proj<<<grid, 256, 0, stream>>>(attn_bf, Wproj, bproj, out);
  }
}

// Round 14
// 45.375 us; speedup vs baseline: 2.4267x; 1.0119x over previous
//
#include <hip/hip_runtime.h>
#include <hip/hip_bf16.h>
#include <math.h>

#define DIM   256
#define NHEAD 8
#define HD    32
#define NTOK  4096
#define GRD   64
#define BATCH 2
#define MTOT  (BATCH * NTOK)   // 8192
#define PLANE (NTOK * HD)      // 131072 elems per (sel,b,h) plane

typedef __attribute__((ext_vector_type(8))) short bf16x8;
typedef __attribute__((ext_vector_type(4))) float f32x4;

static __device__ __forceinline__ unsigned short f2b(float f) {
  __hip_bfloat16 h = __float2bfloat16(f);
  union { __hip_bfloat16 h; unsigned short u; } cv;
  cv.h = h;
  return cv.u;
}

static __device__ __forceinline__ float exp2g(float x) {
  return __builtin_amdgcn_exp2f(x);   // v_exp_f32 (2^x)
}

static __device__ __forceinline__ unsigned cvtpk_bf16(float lo, float hi) {
  unsigned r;
  asm("v_cvt_pk_bf16_f32 %0, %1, %2" : "=v"(r) : "v"(lo), "v"(hi));
  return r;
}

static __device__ __forceinline__ bf16x8 pack8(float4 a0, float4 a1) {
  union { bf16x8 v; unsigned short u[8]; } o;
  o.u[0] = f2b(a0.x); o.u[1] = f2b(a0.y); o.u[2] = f2b(a0.z); o.u[3] = f2b(a0.w);
  o.u[4] = f2b(a1.x); o.u[5] = f2b(a1.y); o.u[6] = f2b(a1.z); o.u[7] = f2b(a1.w);
  return o.v;
}

#define GLDS16(SRC, DST) __builtin_amdgcn_global_load_lds( \
    (const __attribute__((address_space(1))) void*)(SRC),  \
    (__attribute__((address_space(3))) void*)(DST), 16, 0, 0)

// ---------------- GEMM1: qkv = x(fp32) @ Wqkv(fp32)^T -> bf16 planes --------
// 128x128 tile, BK=64 (4 K-iters, 8 barriers). Q/K blocks (bx<4): scatter
// [tok][32] planes. V blocks (bx>=4): LDS-transpose -> V^T [32 d][4096 tok].
__global__ __launch_bounds__(256) void gemm_qkv(const float* __restrict__ A,
                                                const float* __restrict__ Bw,
                                                unsigned short* __restrict__ Cout) {
  const int K = 256;
  __shared__ __align__(16) char smem[73728];
  __hip_bfloat16* As = (__hip_bfloat16*)smem;            // [128*72]
  __hip_bfloat16* Bs = (__hip_bfloat16*)(smem + 36864);  // [128*72]
  const int tid = threadIdx.x;
  const int l = tid & 63, w = tid >> 6;
  const int bm = blockIdx.y * 128, bn = blockIdx.x * 128;
  const int wr = w >> 1, wc = w & 1;
  const int lr = l & 15, kh = l >> 4;

  f32x4 acc[4][4];
  #pragma unroll
  for (int i = 0; i < 4; ++i)
    #pragma unroll
    for (int j = 0; j < 4; ++j)
      acc[i][j] = (f32x4){0.f, 0.f, 0.f, 0.f};

  for (int k0 = 0; k0 < K; k0 += 64) {
    #pragma unroll
    for (int i = 0; i < 4; ++i) {
      const int ch = i * 256 + tid;
      const int row = ch >> 3, col = (ch & 7) * 8;
      const float* ga = A  + (size_t)(bm + row) * K + k0 + col;
      const float* gb = Bw + (size_t)(bn + row) * K + k0 + col;
      float4 a0 = *(const float4*)ga, a1 = *(const float4*)(ga + 4);
      float4 b0 = *(const float4*)gb, b1 = *(const float4*)(gb + 4);
      *(bf16x8*)&As[row * 72 + col] = pack8(a0, a1);
      *(bf16x8*)&Bs[row * 72 + col] = pack8(b0, b1);
    }
    __syncthreads();

    #pragma unroll
    for (int ks = 0; ks < 2; ++ks) {
      bf16x8 af[4], bfr[4];
      #pragma unroll
      for (int f = 0; f < 4; ++f) {
        af[f]  = *(const bf16x8*)&As[(wr * 64 + f * 16 + lr) * 72 + ks * 32 + kh * 8];
        bfr[f] = *(const bf16x8*)&Bs[(wc * 64 + f * 16 + lr) * 72 + ks * 32 + kh * 8];
      }
      #pragma unroll
      for (int fi = 0; fi < 4; ++fi)
        #pragma unroll
        for (int fj = 0; fj < 4; ++fj)
          acc[fi][fj] = __builtin_amdgcn_mfma_f32_16x16x32_bf16(af[fi], bfr[fj], acc[fi][fj], 0, 0, 0);
    }
    __syncthreads();
  }

  if (blockIdx.x < 4) {
    // Q/K planes: plane = sel*16 + bb*8 + hh, layout [tok][32]
    #pragma unroll
    for (int fi = 0; fi < 4; ++fi)
      #pragma unroll
      for (int fj = 0; fj < 4; ++fj)
        #pragma unroll
        for (int rr = 0; rr < 4; ++rr) {
          const int m = bm + wr * 64 + fi * 16 + kh * 4 + rr;
          const int n = bn + wc * 64 + fj * 16 + lr;
          const int sel = n >> 8, rem = n & 255;
          const int hh = rem >> 5, d = rem & 31;
          const int bb = m >> 12, tok = m & 4095;
          Cout[(size_t)(sel * 16 + bb * 8 + hh) * PLANE + tok * 32 + d] =
              f2b(acc[fi][fj][rr]);
        }
  } else {
    // V blocks: transpose through LDS, write V^T [d][tok] coalesced.
    unsigned short* Ts = (unsigned short*)smem;   // [128][136]
    #pragma unroll
    for (int fi = 0; fi < 4; ++fi)
      #pragma unroll
      for (int fj = 0; fj < 4; ++fj)
        #pragma unroll
        for (int rr = 0; rr < 4; ++rr) {
          const int tokl = wr * 64 + fi * 16 + kh * 4 + rr;
          const int dl   = wc * 64 + fj * 16 + lr;
          Ts[tokl * 136 + dl] = f2b(acc[fi][fj][rr]);
        }
    __syncthreads();
    const int dl = tid >> 1, th = (tid & 1) * 64;
    const int dg = (bn - 512) + dl;          // 0..255
    const int hh = dg >> 5, dd = dg & 31;
    const int bb = bm >> 12, tokb = bm & 4095;
    unsigned short* vt = Cout + (size_t)(32 + bb * 8 + hh) * PLANE + dd * 4096 + tokb + th;
    #pragma unroll
    for (int j = 0; j < 8; ++j) {
      union { bf16x8 v; unsigned short u[8]; } o;
      #pragma unroll
      for (int e = 0; e < 8; ++e)
        o.u[e] = Ts[(th + j * 8 + e) * 136 + dl];
      *(bf16x8*)(vt + j * 8) = o.v;
    }
  }
}

// ---------------- GEMM2: out = attn(bf16) @ Wproj(fp32)^T + bias (fp32) -----
// 64x128 tile -> grid (2, 128) = 256 blocks (full GPU; R7/R12-measured).
__global__ __launch_bounds__(256) void gemm_proj(const __hip_bfloat16* __restrict__ A,
                                                 const float* __restrict__ Bw,
                                                 const float* __restrict__ bias,
                                                 float* __restrict__ Cout) {
  const int K = 256, N = 256;
  __shared__ __hip_bfloat16 As[64 * 32];    // linear: global_load_lds dest
  __shared__ __hip_bfloat16 Bs[128 * 40];   // padded: reg-staged
  const int tid = threadIdx.x;
  const int l = tid & 63, w = tid >> 6;
  const int bm = blockIdx.y * 64, bn = blockIdx.x * 128;
  const int wr = w >> 1, wc = w & 1;
  const int lr = l & 15, kh = l >> 4;
  const int lrow = tid >> 2, lcol = (tid & 3) * 8;

  f32x4 acc[2][4];
  #pragma unroll
  for (int i = 0; i < 2; ++i)
    #pragma unroll
    for (int j = 0; j < 4; ++j)
      acc[i][j] = (f32x4){0.f, 0.f, 0.f, 0.f};

  for (int k0 = 0; k0 < K; k0 += 32) {
    {
      const __hip_bfloat16* ga = A + (size_t)(bm + lrow) * K + k0 + lcol;
      GLDS16(ga, &As[w * 512]);
    }
    #pragma unroll
    for (int i = 0; i < 2; ++i) {
      const int row = i * 64 + lrow;
      const float* gb = Bw + (size_t)(bn + row) * K + k0 + lcol;
      float4 b0 = *(const float4*)gb, b1 = *(const float4*)(gb + 4);
      *(bf16x8*)&Bs[row * 40 + lcol] = pack8(b0, b1);
    }
    __syncthreads();

    bf16x8 af[2], bfr[4];
    #pragma unroll
    for (int f = 0; f < 2; ++f)
      af[f] = *(const bf16x8*)&As[(wr * 32 + f * 16 + lr) * 32 + kh * 8];
    #pragma unroll
    for (int f = 0; f < 4; ++f)
      bfr[f] = *(const bf16x8*)&Bs[(wc * 64 + f * 16 + lr) * 40 + kh * 8];
    #pragma unroll
    for (int fi = 0; fi < 2; ++fi)
      #pragma unroll
      for (int fj = 0; fj < 4; ++fj)
        acc[fi][fj] = __builtin_amdgcn_mfma_f32_16x16x32_bf16(af[fi], bfr[fj], acc[fi][fj], 0, 0, 0);
    __syncthreads();
  }

  #pragma unroll
  for (int fi = 0; fi < 2; ++fi)
    #pragma unroll
    for (int fj = 0; fj < 4; ++fj)
      #pragma unroll
      for (int rr = 0; rr < 4; ++rr) {
        const int m = bm + wr * 32 + fi * 16 + kh * 4 + rr;
        const int n = bn + wc * 64 + fj * 16 + lr;
        Cout[(size_t)m * N + n] = acc[fi][fj][rr] + bias[n];
      }
}

// ---------------- MFMA flash-band attention, 2 query-rows per block ---------
// (R12-verified structure + exp2-domain softmax + setprio around MFMA.)
__global__ __launch_bounds__(512, 4) void local_attn_mfma(
    const unsigned short* __restrict__ qkv, const float* __restrict__ temp,
    unsigned short* __restrict__ attn_out) {
  __shared__ __align__(16) unsigned short Ks[512 * 32];   // 32768 B
  __shared__ __align__(16) unsigned short Vt[32 * 512];   // 32768 B

  const int P = blockIdx.x;
  const int L = (P & 7) * 64 + (P >> 3);    // XCD-chunked remap (512 = 8*64)
  const int plane = L >> 5, rp = L & 31;
  const int b = plane >> 3, h = plane & 7;
  const int tid = threadIdx.x;
  const int l = tid & 63, wv = tid >> 6;
  const int qr = wv >> 2, wq = wv & 3;
  const int q15 = l & 15, sg = l >> 4;
  const int r = rp * 2 + qr;                // this wave's query grid-row

  // log2-domain scale: softmax(x*s) == softmax2(x*s*log2e)
  const float scale2 = 0.17677669529663687f * 1.44269504088896f * temp[0];

  const unsigned short* qplane  = qkv + (size_t)(b * 8 + h) * PLANE;
  const unsigned short* kplane  = qplane + (size_t)16 * PLANE;
  const unsigned short* vtplane = qplane + (size_t)32 * PLANE;

  const int rbase = rp * 2 - 3;

  // ---- stage K: 512 band-tokens x 64B rows (2048 16B chunks) ---------------
  #pragma unroll
  for (int i = 0; i < 4; ++i) {
    const int ch = i * 512 + tid;
    const int tok = ch >> 2, jjp = ch & 3;
    const int ri = tok >> 6, kloc = tok & 63;
    int row = rbase + ri; row = row < 0 ? 0 : (row > 63 ? 63 : row);
    const int jl = jjp ^ ((tok >> 1) & 3);
    const unsigned short* src = kplane + (size_t)(row * 64 + kloc) * 32 + jl * 8;
    GLDS16(src, &Ks[(i * 512 + (tid & ~63)) * 8]);
  }
  // ---- stage V^T: 32 d-rows x 512 tokens (2048 16B chunks) -----------------
  #pragma unroll
  for (int i = 0; i < 4; ++i) {
    const int ch = i * 512 + tid;
    const int d = ch >> 6, chp = ch & 63;
    const int chl = chp ^ (d & 7);
    const int ri = chl >> 3, part = chl & 7;
    int row = rbase + ri; row = row < 0 ? 0 : (row > 63 ? 63 : row);
    const unsigned short* src = vtplane + (size_t)d * 4096 + row * 64 + part * 8;
    GLDS16(src, &Vt[(i * 512 + (tid & ~63)) * 8]);
  }

  // ---- Q fragment (B-operand style): Q[q15][sg*8..+8] ----------------------
  const bf16x8 qf = *(const bf16x8*)(qplane + (size_t)(r * 64 + wq * 16 + q15) * 32 + sg * 8);

  __syncthreads();

  const int qcol = wq * 16 + q15;
  float m_run = -INFINITY, l_run = 0.f;
  f32x4 Od[2];
  Od[0] = (f32x4){0.f, 0.f, 0.f, 0.f};
  Od[1] = (f32x4){0.f, 0.f, 0.f, 0.f};
  const f32x4 zf = {0.f, 0.f, 0.f, 0.f};
  const int laA = ((l >> 4) & 1) * 32 + q15;   // source lane for P-frag low keys
  const int laB = laA + 16;
  const bool hiG = (l & 32) != 0;              // group>=2 -> use kt 2h+1

  #pragma unroll
  for (int c = 0; c < 7; ++c) {
    const int rr_c = r - 3 + c;                // wave-uniform
    if (rr_c >= 0 && rr_c <= 63) {
      const int bri = c + qr;                  // staged band-row index 0..8
      // ---- QK^T: 4 S^T tiles ----------------------------------------------
      f32x4 st[4];
      __builtin_amdgcn_s_setprio(1);
      #pragma unroll
      for (int kt = 0; kt < 4; ++kt) {
        const int tok = bri * 64 + kt * 16 + q15;
        const bf16x8 kf = *(const bf16x8*)((const char*)Ks + tok * 64 +
                                           ((sg ^ ((tok >> 1) & 3)) << 4));
        st[kt] = __builtin_amdgcn_mfma_f32_16x16x32_bf16(kf, qf, zf, 0, 0, 0);
      }
      __builtin_amdgcn_s_setprio(0);
      // ---- mask + scale(log2) + chunk max ---------------------------------
      float mc = -INFINITY;
      #pragma unroll
      for (int kt = 0; kt < 4; ++kt)
        #pragma unroll
        for (int rg = 0; rg < 4; ++rg) {
          const int keyloc = kt * 16 + sg * 4 + rg;
          const bool ok = (unsigned)(keyloc - qcol + 3) <= 6u;
          const float v = ok ? st[kt][rg] * scale2 : -INFINITY;
          st[kt][rg] = v;
          mc = fmaxf(mc, v);
        }
      mc = fmaxf(mc, __shfl_xor(mc, 16));
      mc = fmaxf(mc, __shfl_xor(mc, 32));
      const float mnew = fmaxf(m_run, mc);
      const float alpha = exp2g(m_run - mnew);   // 0 on first chunk
      float lc = 0.f;
      #pragma unroll
      for (int kt = 0; kt < 4; ++kt)
        #pragma unroll
        for (int rg = 0; rg < 4; ++rg) {
          const float e = exp2g(st[kt][rg] - mnew);   // masked -> 0
          st[kt][rg] = e;
          lc += e;
        }
      lc += __shfl_xor(lc, 16);
      lc += __shfl_xor(lc, 32);
      l_run = l_run * alpha + lc;
      m_run = mnew;
      Od[0] *= alpha;
      Od[1] *= alpha;

      // ---- pack p to bf16 pairs, exchange into P B-frags, PV --------------
      unsigned pkw[8];
      #pragma unroll
      for (int kt = 0; kt < 4; ++kt) {
        pkw[kt * 2 + 0] = cvtpk_bf16(st[kt][0], st[kt][1]);
        pkw[kt * 2 + 1] = cvtpk_bf16(st[kt][2], st[kt][3]);
      }
      #pragma unroll
      for (int hf = 0; hf < 2; ++hf) {
        unsigned wA[2], wB[2];
        #pragma unroll
        for (int w2 = 0; w2 < 2; ++w2) {
          const unsigned a0 = (unsigned)__shfl((int)pkw[(2 * hf) * 2 + w2], laA);
          const unsigned a1 = (unsigned)__shfl((int)pkw[(2 * hf + 1) * 2 + w2], laA);
          wA[w2] = hiG ? a1 : a0;
          const unsigned b0 = (unsigned)__shfl((int)pkw[(2 * hf) * 2 + w2], laB);
          const unsigned b1 = (unsigned)__shfl((int)pkw[(2 * hf + 1) * 2 + w2], laB);
          wB[w2] = hiG ? b1 : b0;
        }
        union { unsigned u[4]; bf16x8 v; } pf;
        pf.u[0] = wA[0]; pf.u[1] = wA[1]; pf.u[2] = wB[0]; pf.u[3] = wB[1];
        __builtin_amdgcn_s_setprio(1);
        #pragma unroll
        for (int dt = 0; dt < 2; ++dt) {
          const int d = dt * 16 + q15;
          const int chl = bri * 8 + hf * 4 + sg;
          const bf16x8 vf = *(const bf16x8*)((const char*)Vt + d * 1024 +
                                             ((chl ^ (d & 7)) << 4));
          Od[dt] = __builtin_amdgcn_mfma_f32_16x16x32_bf16(vf, pf.v, Od[dt], 0, 0, 0);
        }
        __builtin_amdgcn_s_setprio(0);
      }
    }
  }

  // ---- normalize + store O^T (lane: d = dt*16+sg*4+rg, q = q15) ------------
  const float invl = 1.0f / l_run;
  #pragma unroll
  for (int dt = 0; dt < 2; ++dt) {
    const unsigned w0 = cvtpk_bf16(Od[dt][0] * invl, Od[dt][1] * invl);
    const unsigned w1 = cvtpk_bf16(Od[dt][2] * invl, Od[dt][3] * invl);
    unsigned short* dst = attn_out + (size_t)(b * 4096 + r * 64 + qcol) * 256 +
                          h * 32 + dt * 16 + sg * 4;
    uint2 uu; uu.x = w0; uu.y = w1;
    *(uint2*)dst = uu;
  }
}

extern "C" void kernel_launch(void* const* d_in, const int* in_sizes, int n_in,
                              void* d_out, int out_size, void* d_ws, size_t ws_size,
                              hipStream_t stream) {
  const float* x     = (const float*)d_in[0];
  const float* Wqkv  = (const float*)d_in[1];
  const float* Wproj = (const float*)d_in[2];
  const float* bproj = (const float*)d_in[3];
  const float* temp  = (const float*)d_in[4];
  float* out = (float*)d_out;

  // workspace layout (bytes):
  //   [0, 12582912)            qkv bf16 planes: 48 x 131072 elems
  //                            (Q/K planes [tok][32]; V planes transposed [32][4096])
  //   [25165824, 29360128)     attn_bf16 [8192][256]
  char* ws = (char*)d_ws;
  unsigned short* qkv_bf  = (unsigned short*)ws;
  __hip_bfloat16* attn_bf = (__hip_bfloat16*)(ws + 25165824);

  // 1) qkv = x @ Wqkv^T (fused fp32->bf16), Q/K planar + V transposed
  {
    dim3 grid(3 * DIM / 128, MTOT / 128);   // (6, 64)
    gemm_qkv<<<grid, 256, 0, stream>>>(x, Wqkv, qkv_bf);
  }
  // 2) MFMA flash-band attention (2 query-rows/block) -> attn_bf
  local_attn_mfma<<<BATCH * NHEAD * (GRD / 2), 512, 0, stream>>>(
      qkv_bf, temp, (unsigned short*)attn_bf);
  // 3) out = attn @ Wproj^T + bias
  {
    dim3 grid(DIM / 128, MTOT / 64);        // (2, 128) = 256 blocks
    gemm_proj<<<grid, 256, 0, stream>>>(attn_bf, Wproj, bproj, out);
  }
}